// Round 11
// baseline (169.184 us; speedup 1.0000x reference)
//
#include <hip/hip_runtime.h>

typedef short bf16x8 __attribute__((ext_vector_type(8)));
typedef float f32x4 __attribute__((ext_vector_type(4)));
typedef unsigned short u16;

#define NNODE 196608
#define FF 32
#define COLS 256   // UP * OUT_FEATURES
#define KTOT 288   // KK * FF
#define WELEMS (COLS * KTOT)   // 73728 elems = 144 KB bf16
#define TPB 12                 // tiles per block (3072 / 256); tile = 64 nodes

__device__ __forceinline__ u16 f2bf(float f) {
    unsigned u = __builtin_bit_cast(unsigned, f);
    return (u16)((u + 0x7fffu + ((u >> 16) & 1u)) >> 16);  // RTNE
}

// prep 1: x (2,N,32) f32 -> xb2 bf16 INTERLEAVED: xb2[node][0:32]=t0 feats,
// xb2[node][32:64]=t1 feats -> one 128-B line per node (gather = 1 line).
__global__ void cvt_x(const float* __restrict__ x, u16* __restrict__ xb2, int n8) {
    int i = blockIdx.x * blockDim.x + threadIdx.x;
    if (i >= n8) return;
    int og   = i * 8;           // output element index (u16 units)
    int node = og >> 6;
    int rem  = og & 63;
    int s    = rem >> 5;        // t-slice
    int f0   = rem & 31;        // feature start (0,8,16,24)
    const float* src = x + ((size_t)s * NNODE + node) * FF + f0;
    f32x4 v0 = *(const f32x4*)src;
    f32x4 v1 = *(const f32x4*)(src + 4);
    union { u16 h[8]; bf16x8 v; } r;
    #pragma unroll
    for (int j = 0; j < 4; ++j) r.h[j] = f2bf(v0[j]);
    #pragma unroll
    for (int j = 0; j < 4; ++j) r.h[4 + j] = f2bf(v1[j]);
    *((bf16x8*)xb2 + i) = r.v;
}

// prep 2: W (K,F,UP,O) f32 -> Wt bf16, MFMA fragment-linear:
// Wt[f*512 + lane*8 + e] = W[kf][c], f = kk*16+ct, c = ct*16+(lane&15),
// kf = kk*32 + (lane>>4)*8 + e. Wave ds_read_b128 of a frag: lane-linear.
__global__ void cvt_w(const float* __restrict__ W, u16* __restrict__ Wt) {
    int gid = blockIdx.x * 256 + threadIdx.x;   // 73728 total
    int f      = gid >> 9;
    int within = gid & 511;
    int lane   = within >> 3;
    int e      = within & 7;
    int kk = f >> 4, ct = f & 15;
    int cl = lane & 15, q = lane >> 4;
    int c  = ct * 16 + cl;
    int kf = kk * 32 + q * 8 + e;
    Wt[gid] = f2bf(W[(size_t)kf * COLS + c]);
}

// main: grid 256 (1 blk/CU via 145 KB LDS), 512 thr = 8 waves =
// 4 node-groups x 2 col-halves. Tile = 64 nodes x 2t x 256 cols, 12/block.
// Wave: 16 nodes x 2t x 128 cols -> acc = 2 x 8 f32x4 = 64 AGPRs (half of
// R8) which frees the ARCH half for an 18-gather full-tile prefetch.
// FIFO KEY (m135: vmcnt positional, in-order): ALL of tile tt+1's gathers
// are issued BEFORE tile tt's stores, so the next kk-loop (pure LDS+MFMA)
// consumes only gathers OLDER than the stores -> consume-waits leave the
// store backlog outstanding; it drains under a full tile of compute.
// Col-pair waves gather identical 128-B lines -> duplicate is an L2 hit
// (R2 vs R5 evidence). Raw s_barrier per tile (no vmcnt drain).
__global__ __launch_bounds__(512, 2) void updown_main(
    const u16* __restrict__ xb2, const u16* __restrict__ Wt,
    const int* __restrict__ adjc, const float* __restrict__ bias,
    float* __restrict__ out)
{
    __shared__ __align__(16) u16 wlds[WELEMS];   // 144 KB, read-only after load
    __shared__ __align__(16) float blds[COLS];   // 1 KB bias

    const int tid = threadIdx.x;

    #pragma unroll
    for (int i = 0; i < 18; ++i)
        *(bf16x8*)(wlds + i * 4096 + tid * 8) =
            *(const bf16x8*)(Wt + i * 4096 + tid * 8);
    if (tid < 64) ((f32x4*)blds)[tid] = ((const f32x4*)bias)[tid];
    __syncthreads();   // the only full barrier

    const int w    = tid >> 6;
    const int lane = tid & 63;
    const int l15  = lane & 15;
    const int q    = lane >> 4;
    const int g    = w >> 1;               // node-group 0..3
    const int wc   = w & 1;                // col-half
    const u16* wbase = wlds + (size_t)(wc * 8) * 512 + lane * 8;  // + kk*8192 + ctl*512
    const float* bb  = blds + wc * 128 + q * 4;                   // + ctl*16

    const int node0 = blockIdx.x * (TPB * 64) + g * 16 + l15;

    // tile-0 prologue: all 18 gathers in flight before the loop
    bf16x8 g0[9], g1[9];
    {
        const int* arow = adjc + (size_t)node0 * 9;
        int idxA[9];
        #pragma unroll
        for (int k = 0; k < 9; ++k) idxA[k] = arow[k];
        #pragma unroll
        for (int k = 0; k < 9; ++k) {
            const u16* p = xb2 + (size_t)idxA[k] * 64 + q * 8;
            g0[k] = *(const bf16x8*)p;
            g1[k] = *(const bf16x8*)(p + 32);
        }
    }

    for (int tt = 0; tt < TPB; ++tt) {
        const int node = node0 + tt * 64;

        // acc init = bias (LDS reads -> lgkm counter, not the vmcnt FIFO)
        f32x4 acc0[8], acc1[8];
        #pragma unroll
        for (int ct = 0; ct < 8; ++ct) {
            f32x4 bq = *(const f32x4*)(bb + ct * 16);
            acc0[ct] = bq;
            acc1[ct] = bq;
        }

        // K-loop: pure LDS + MFMA; consumes only pre-store gathers
        #pragma unroll
        for (int kk = 0; kk < 9; ++kk) {
            const u16* wk = wbase + kk * 8192;
            #pragma unroll
            for (int ct = 0; ct < 8; ++ct) {
                bf16x8 af = *(const bf16x8*)(wk + ct * 512);
                acc0[ct] = __builtin_amdgcn_mfma_f32_16x16x32_bf16(af, g0[kk], acc0[ct], 0, 0, 0);
                acc1[ct] = __builtin_amdgcn_mfma_f32_16x16x32_bf16(af, g1[kk], acc1[ct], 0, 0, 0);
            }
        }

        // SEAM: next tile's idx + ALL 18 gathers FIRST (older than stores)
        if (tt < TPB - 1) {
            const int* arow = adjc + (size_t)(node + 64) * 9;
            int idxN[9];
            #pragma unroll
            for (int k = 0; k < 9; ++k) idxN[k] = arow[k];
            #pragma unroll
            for (int k = 0; k < 9; ++k) {
                const u16* p = xb2 + (size_t)idxN[k] * 64 + q * 8;
                g0[k] = *(const bf16x8*)p;
                g1[k] = *(const bf16x8*)(p + 32);
            }
        }
        __builtin_amdgcn_sched_barrier(0);   // pin: gathers precede stores

        // ... THEN stores; they drain lazily under the next tile's compute
        float* o0 = out + (size_t)node * COLS + wc * 128 + q * 4;
        float* o1 = o0 + (size_t)NNODE * COLS;
        #pragma unroll
        for (int ct = 0; ct < 8; ++ct) {
            *(f32x4*)(o0 + ct * 16) = acc0[ct];
            *(f32x4*)(o1 + ct * 16) = acc1[ct];
        }

        // phase-lock waves (keeps col-pair L2 line sharing); raw barrier:
        // NO vmcnt drain — stores stay in flight under next tile's compute
        __builtin_amdgcn_s_barrier();
    }
}

extern "C" void kernel_launch(void* const* d_in, const int* in_sizes, int n_in,
                              void* d_out, int out_size, void* d_ws, size_t ws_size,
                              hipStream_t stream) {
    const float* x    = (const float*)d_in[0];
    const int*   adjc = (const int*)d_in[1];
    const float* W    = (const float*)d_in[2];
    const float* b    = (const float*)d_in[3];
    float* out = (float*)d_out;

    u16* xb2 = (u16*)d_ws;                           // 196608*64 bf16 = 25.2 MB
    u16* Wt  = xb2 + (size_t)NNODE * 64;             // 73728 bf16 = 144 KB

    cvt_x<<<dim3(6144), dim3(256), 0, stream>>>(x, xb2, 1572864);
    cvt_w<<<dim3(288), dim3(256), 0, stream>>>(W, Wt);
    updown_main<<<dim3(256), dim3(512), 0, stream>>>(xb2, Wt, adjc, b, out);
}

// Round 12
// 156.755 us; speedup vs baseline: 1.0793x; 1.0793x over previous
//
#include <hip/hip_runtime.h>

typedef short bf16x8 __attribute__((ext_vector_type(8)));
typedef float f32x4 __attribute__((ext_vector_type(4)));
typedef unsigned short u16;

#define NNODE 196608
#define FF 32
#define COLS 256   // UP * OUT_FEATURES
#define KTOT 288   // KK * FF
#define WELEMS (COLS * KTOT)   // 73728 elems = 144 KB bf16
#define TPB 6                  // tiles per block (1536 / 256)

__device__ __forceinline__ u16 f2bf(float f) {
    unsigned u = __builtin_bit_cast(unsigned, f);
    return (u16)((u + 0x7fffu + ((u >> 16) & 1u)) >> 16);  // RTNE
}

// prep 1: x (2,N,32) f32 -> xb2 bf16 INTERLEAVED: xb2[node][0:32]=t0 feats,
// xb2[node][32:64]=t1 feats -> one 128-B line per node (gather = 1 line).
__global__ void cvt_x(const float* __restrict__ x, u16* __restrict__ xb2, int n8) {
    int i = blockIdx.x * blockDim.x + threadIdx.x;
    if (i >= n8) return;
    int og   = i * 8;           // output element index (u16 units)
    int node = og >> 6;
    int rem  = og & 63;
    int s    = rem >> 5;        // t-slice
    int f0   = rem & 31;        // feature start (0,8,16,24)
    const float* src = x + ((size_t)s * NNODE + node) * FF + f0;
    f32x4 v0 = *(const f32x4*)src;
    f32x4 v1 = *(const f32x4*)(src + 4);
    union { u16 h[8]; bf16x8 v; } r;
    #pragma unroll
    for (int j = 0; j < 4; ++j) r.h[j] = f2bf(v0[j]);
    #pragma unroll
    for (int j = 0; j < 4; ++j) r.h[4 + j] = f2bf(v1[j]);
    *((bf16x8*)xb2 + i) = r.v;
}

// prep 2: W (K,F,UP,O) f32 -> Wt bf16, MFMA fragment-linear:
// Wt[f*512 + lane*8 + e] = W[kf][c], f = kk*16+ct, c = ct*16+(lane&15),
// kf = kk*32 + (lane>>4)*8 + e. Wave ds_read_b128 of a frag: lane-linear.
__global__ void cvt_w(const float* __restrict__ W, u16* __restrict__ Wt) {
    int gid = blockIdx.x * 256 + threadIdx.x;   // 73728 total
    int f      = gid >> 9;
    int within = gid & 511;
    int lane   = within >> 3;
    int e      = within & 7;
    int kk = f >> 4, ct = f & 15;
    int cl = lane & 15, q = lane >> 4;
    int c  = ct * 16 + cl;
    int kf = kk * 32 + q * 8 + e;
    Wt[gid] = f2bf(W[(size_t)kf * COLS + c]);
}

// main: grid 256 (1 blk/CU via 145 KB LDS), 512 thr = 8 waves = 4
// node-groups x 2 col-halves. Tile = 128 nodes x 2t x 256 cols, 6/block.
// Wave: 32 nodes (2 subgroups of 16) x 2t x 128 cols -> per k-step the
// SAME 8 W-frags feed 32 MFMAs (R8: 16 frags for 32 MFMAs), halving
// per-CU LDS-read volume (1.15 MB -> 576 KB per tile). acc = 2x2x8
// f32x4 = 128 regs (same as R8). Gathers stay depth-2 and SPREAD
// (4/k-step — R10/R11 lesson: bursty prefetch stalls the TA queue).
// Col-pair waves re-request identical 128-B lines -> L2 hits (C=2).
// R6/R7 lesson: no live state across the tile seam.
__global__ __launch_bounds__(512, 2) void updown_main(
    const u16* __restrict__ xb2, const u16* __restrict__ Wt,
    const int* __restrict__ adjc, const float* __restrict__ bias,
    float* __restrict__ out)
{
    __shared__ __align__(16) u16 wlds[WELEMS];   // 144 KB, read-only after load
    __shared__ __align__(16) float blds[COLS];   // 1 KB bias

    const int tid = threadIdx.x;

    #pragma unroll
    for (int i = 0; i < 18; ++i)
        *(bf16x8*)(wlds + i * 4096 + tid * 8) =
            *(const bf16x8*)(Wt + i * 4096 + tid * 8);
    if (tid < 64) ((f32x4*)blds)[tid] = ((const f32x4*)bias)[tid];
    __syncthreads();   // the only full barrier

    const int w    = tid >> 6;
    const int lane = tid & 63;
    const int l15  = lane & 15;
    const int q    = lane >> 4;
    const int ng   = w >> 1;               // node-group 0..3
    const int ch   = w & 1;                // col-half
    // frag address: (kk*16 + ch*8 + ct)*512 + lane*8
    const u16* wbase = wlds + (size_t)(ch * 8) * 512 + lane * 8;
    const float* bb  = blds + ch * 128 + q * 4;   // + ct*16

    const int node0 = blockIdx.x * (TPB * 128) + ng * 32 + l15;

    for (int tt = 0; tt < TPB; ++tt) {
        const int node  = node0 + tt * 128;
        const int* ar0 = adjc + (size_t)node * 9;          // subgroup 0
        const int* ar1 = adjc + (size_t)(node + 16) * 9;   // subgroup 1

        // tile prologue: per subgroup, 2 gathers in flight + idx one ahead
        int i00 = ar0[0], i10 = ar1[0];
        int i01 = ar0[1], i11 = ar1[1];
        const u16* p00 = xb2 + (size_t)i00 * 64 + q * 8;
        const u16* p10 = xb2 + (size_t)i10 * 64 + q * 8;
        const u16* p01 = xb2 + (size_t)i01 * 64 + q * 8;
        const u16* p11 = xb2 + (size_t)i11 * 64 + q * 8;
        bf16x8 aC0t0 = *(const bf16x8*)p00, aC0t1 = *(const bf16x8*)(p00 + 32);
        bf16x8 aC1t0 = *(const bf16x8*)p10, aC1t1 = *(const bf16x8*)(p10 + 32);
        bf16x8 aN0t0 = *(const bf16x8*)p01, aN0t1 = *(const bf16x8*)(p01 + 32);
        bf16x8 aN1t0 = *(const bf16x8*)p11, aN1t1 = *(const bf16x8*)(p11 + 32);
        int idxP0 = ar0[2], idxP1 = ar1[2];

        // acc init = bias (lgkm counter — doesn't touch the vmcnt FIFO)
        f32x4 a0t0[8], a0t1[8], a1t0[8], a1t1[8];   // [sub][t][ct]
        #pragma unroll
        for (int ct = 0; ct < 8; ++ct) {
            f32x4 bq = *(const f32x4*)(bb + ct * 16);
            a0t0[ct] = bq; a0t1[ct] = bq;
            a1t0[ct] = bq; a1t1[ct] = bq;
        }

        #pragma unroll
        for (int kk = 0; kk < 9; ++kk) {
            bf16x8 aNN0t0, aNN0t1, aNN1t0, aNN1t1;
            if (kk < 7) {   // gather kk+2 for both subgroups (spread issue)
                const u16* g0 = xb2 + (size_t)idxP0 * 64 + q * 8;
                const u16* g1 = xb2 + (size_t)idxP1 * 64 + q * 8;
                aNN0t0 = *(const bf16x8*)g0; aNN0t1 = *(const bf16x8*)(g0 + 32);
                aNN1t0 = *(const bf16x8*)g1; aNN1t1 = *(const bf16x8*)(g1 + 32);
            }
            if (kk < 6) { idxP0 = ar0[kk + 3]; idxP1 = ar1[kk + 3]; }

            const u16* wk = wbase + kk * 8192;
            #pragma unroll
            for (int ct = 0; ct < 8; ++ct) {
                bf16x8 af = *(const bf16x8*)(wk + ct * 512);
                a0t0[ct] = __builtin_amdgcn_mfma_f32_16x16x32_bf16(af, aC0t0, a0t0[ct], 0, 0, 0);
                a0t1[ct] = __builtin_amdgcn_mfma_f32_16x16x32_bf16(af, aC0t1, a0t1[ct], 0, 0, 0);
                a1t0[ct] = __builtin_amdgcn_mfma_f32_16x16x32_bf16(af, aC1t0, a1t0[ct], 0, 0, 0);
                a1t1[ct] = __builtin_amdgcn_mfma_f32_16x16x32_bf16(af, aC1t1, a1t1[ct], 0, 0, 0);
            }
            if (kk < 8) {
                aC0t0 = aN0t0; aC0t1 = aN0t1;
                aC1t0 = aN1t0; aC1t1 = aN1t1;
            }
            if (kk < 7) {
                aN0t0 = aNN0t0; aN0t1 = aNN0t1;
                aN1t0 = aNN1t0; aN1t1 = aNN1t1;
            }
        }

        // stores: lane-contiguous f32x4 (node from l15, col = ch*128+ct*16+q*4)
        {
            float* o = out + (size_t)node * COLS + ch * 128 + q * 4;
            float* p0 = o;                                   // sub0 t0
            float* p1 = o + (size_t)NNODE * COLS;            // sub0 t1
            float* p2 = o + 16 * COLS;                       // sub1 t0
            float* p3 = p2 + (size_t)NNODE * COLS;           // sub1 t1
            #pragma unroll
            for (int ct = 0; ct < 8; ++ct) {
                *(f32x4*)(p0 + ct * 16) = a0t0[ct];
                *(f32x4*)(p1 + ct * 16) = a0t1[ct];
                *(f32x4*)(p2 + ct * 16) = a1t0[ct];
                *(f32x4*)(p3 + ct * 16) = a1t1[ct];
            }
        }

        // phase-lock the 8 waves (gather L2 line sharing); raw barrier:
        // NO vmcnt drain — stores stay in flight under next tile's compute
        __builtin_amdgcn_s_barrier();
    }
}

extern "C" void kernel_launch(void* const* d_in, const int* in_sizes, int n_in,
                              void* d_out, int out_size, void* d_ws, size_t ws_size,
                              hipStream_t stream) {
    const float* x    = (const float*)d_in[0];
    const int*   adjc = (const int*)d_in[1];
    const float* W    = (const float*)d_in[2];
    const float* b    = (const float*)d_in[3];
    float* out = (float*)d_out;

    u16* xb2 = (u16*)d_ws;                           // 196608*64 bf16 = 25.2 MB
    u16* Wt  = xb2 + (size_t)NNODE * 64;             // 73728 bf16 = 144 KB

    cvt_x<<<dim3(6144), dim3(256), 0, stream>>>(x, xb2, 1572864);
    cvt_w<<<dim3(288), dim3(256), 0, stream>>>(W, Wt);
    updown_main<<<dim3(256), dim3(512), 0, stream>>>(xb2, Wt, adjc, b, out);
}